// Round 4
// baseline (167.571 us; speedup 1.0000x reference)
//
#include <hip/hip_runtime.h>
#include <hip/hip_bf16.h>
#include <float.h>
#include <limits.h>

#define NNODES 16384
#define KNB 8
#define HIDC 128
#define KNN_CAP 2560   // LDS candidate window (float4 each = 40KB)

// -------- DPP helpers (pure-VALU cross-lane) --------
__device__ __forceinline__ unsigned int dpp_shr1_u32(unsigned int v) {
  // row_shr:1 (0x111); bound_ctrl=1 -> invalid lanes (lane 0 of each row) read 0
  return (unsigned int)__builtin_amdgcn_update_dpp(0, (int)v, 0x111, 0xF, 0xF, true);
}
__device__ __forceinline__ float wave_sum(float x) {
  x += __int_as_float(__builtin_amdgcn_update_dpp(0, __float_as_int(x), 0xB1, 0xF, 0xF, true));  // quad xor1
  x += __int_as_float(__builtin_amdgcn_update_dpp(0, __float_as_int(x), 0x4E, 0xF, 0xF, true));  // quad xor2
  x += __int_as_float(__builtin_amdgcn_update_dpp(0, __float_as_int(x), 0x124, 0xF, 0xF, true)); // row_ror:4
  x += __int_as_float(__builtin_amdgcn_update_dpp(0, __float_as_int(x), 0x128, 0xF, 0xF, true)); // row_ror:8
  float r0 = __int_as_float(__builtin_amdgcn_readlane(__float_as_int(x), 0));
  float r1 = __int_as_float(__builtin_amdgcn_readlane(__float_as_int(x), 16));
  float r2 = __int_as_float(__builtin_amdgcn_readlane(__float_as_int(x), 32));
  float r3 = __int_as_float(__builtin_amdgcn_readlane(__float_as_int(x), 48));
  return (r0 + r1) + (r2 + r3);
}

// Insert all survivor keys (marked in mask m) into the distributed sorted
// top-8 list (lanes 0..7 hold llo/lhi ascending). In-loop tau re-check skips
// keys made stale by earlier inserts in the same mask.
__device__ __forceinline__ void insert_survivors(
    unsigned long long m, unsigned int c_lo, unsigned int c_hi,
    unsigned int& llo, unsigned int& lhi, unsigned long long& tau) {
  while (m) {
    int src = __builtin_ctzll(m);
    m &= m - 1;
    unsigned int nlo = (unsigned int)__builtin_amdgcn_readlane((int)c_lo, src);
    unsigned int nhi = (unsigned int)__builtin_amdgcn_readlane((int)c_hi, src);
    unsigned long long nk = ((unsigned long long)nhi << 32) | nlo;
    if (nk >= tau) continue;          // stale survivor: tau tightened already
    unsigned int plo = dpp_shr1_u32(llo);
    unsigned int phi = dpp_shr1_u32(lhi);
    unsigned long long pk = ((unsigned long long)phi << 32) | plo;
    unsigned long long ck = ((unsigned long long)lhi << 32) | llo;
    if (nk < ck) {
      unsigned long long r = (pk > nk) ? pk : nk;
      llo = (unsigned int)r; lhi = (unsigned int)(r >> 32);
    }
    tau = (((unsigned long long)(unsigned int)__builtin_amdgcn_readlane((int)lhi, 7)) << 32)
          | (unsigned int)__builtin_amdgcn_readlane((int)llo, 7);
  }
}

// ---------------- segment table: seg[b] = lower_bound(batch, b), b in [0,8] ----------------
__global__ void seg_kernel(const int* __restrict__ batch, int* __restrict__ seg) {
  int b = threadIdx.x;
  if (b > 8) return;
  int lo = 0, hi = NNODES;
  while (lo < hi) { int m = (lo + hi) >> 1; if (batch[m] < b) lo = m + 1; else hi = m; }
  seg[b] = lo;
}

// ---------------- KNN ----------------
// Block = 512 threads (8 waves) = 8 consecutive query nodes sharing one LDS
// candidate window. Cold start: first 64 candidates (1/lane, global reads).
// Main loop: 256 candidates/iter (4/lane, strided -> conflict-free b128).
__global__ __launch_bounds__(512) void knn_kernel(
    const float* __restrict__ coord, const int* __restrict__ batch,
    const int* __restrict__ seg, int* __restrict__ knn) {
  __shared__ float4 tile[KNN_CAP];
  int t = threadIdx.x;
  int lane = t & 63;
  int n0 = blockIdx.x * 8;
  int n = n0 + (t >> 6);

  int b0 = batch[n0], b7 = batch[n0 + 7], bw = batch[n];
  int smin = seg[b0];
  int emax = seg[b7 + 1];
  int s_w = seg[bw];
  int e_w = seg[bw + 1];
  int win_end = min(emax, smin + KNN_CAP);
  int cnt = win_end - smin;

  // cooperative fill of candidate window
  for (int i = t; i < cnt; i += 512) {
    const float* cp = coord + (size_t)(smin + i) * 3;
    tile[i] = make_float4(cp[0], cp[1], cp[2], 0.f);
  }

  float cx = coord[n*3+0], cy = coord[n*3+1], cz = coord[n*3+2];

  unsigned long long tau = ~0ull;
  unsigned int llo = 0xFFFFFFFFu, lhi = 0xFFFFFFFFu;  // lanes 0..7: sorted keys

  // --- cold start: first 64 candidates, global reads, in-loop tau recheck ---
  {
    int j = s_w + lane;
    bool ok = j < e_w;
    int jc = ok ? j : s_w;
    float dx = __fsub_rn(coord[jc*3+0], cx);
    float dy = __fsub_rn(coord[jc*3+1], cy);
    float dz = __fsub_rn(coord[jc*3+2], cz);
    float d = __fadd_rn(__fadd_rn(__fmul_rn(dx,dx), __fmul_rn(dy,dy)), __fmul_rn(dz,dz));
    unsigned int klo = (unsigned int)j;
    unsigned int khi = __float_as_uint(d);
    insert_survivors(__ballot(ok), klo, khi, llo, lhi, tau);
  }

  __syncthreads();

  // --- main loop: 256 candidates/iter, 4 strided per lane ---
  int lo_i = s_w - smin;
  int hi_i = min(e_w, win_end) - smin;
  for (int base = lo_i + 64; base < hi_i; base += 256) {
    unsigned long long k[4];
    #pragma unroll
    for (int q = 0; q < 4; ++q) {
      int i = base + lane + 64 * q;
      bool ok = i < hi_i;
      float4 c = tile[ok ? i : 0];
      float dx = __fsub_rn(c.x, cx);
      float dy = __fsub_rn(c.y, cy);
      float dz = __fsub_rn(c.z, cz);
      float d = __fadd_rn(__fadd_rn(__fmul_rn(dx,dx), __fmul_rn(dy,dy)), __fmul_rn(dz,dz));
      k[q] = ok ? (((unsigned long long)__float_as_uint(d) << 32) | (unsigned int)(smin + i))
                : ~0ull;
    }
    #pragma unroll
    for (int q = 0; q < 4; ++q) {
      unsigned long long m = __ballot(k[q] < tau);
      if (m) insert_survivors(m, (unsigned int)k[q], (unsigned int)(k[q] >> 32), llo, lhi, tau);
    }
  }

  // --- global tail: window overflow / graph straddle (rare) ---
  for (int base = max(s_w + 64, win_end); base < e_w; base += 64) {
    int j = base + lane;
    bool ok = j < e_w;
    int jc = ok ? j : s_w;
    float dx = __fsub_rn(coord[jc*3+0], cx);
    float dy = __fsub_rn(coord[jc*3+1], cy);
    float dz = __fsub_rn(coord[jc*3+2], cz);
    float d = __fadd_rn(__fadd_rn(__fmul_rn(dx,dx), __fmul_rn(dy,dy)), __fmul_rn(dz,dz));
    unsigned long long ckey = ok
        ? (((unsigned long long)__float_as_uint(d) << 32) | (unsigned int)j)
        : ~0ull;
    unsigned long long m = __ballot(ckey < tau);
    if (m) insert_survivors(m, (unsigned int)ckey, (unsigned int)(ckey >> 32), llo, lhi, tau);
  }
  if (lane < KNB) knn[n*KNB + lane] = (int)llo;
}

// ---------------- xl = x@Wl + bl ; xr = x@Wr + br  (fused, 32-node tiles) ----------------
template<int K>
__global__ __launch_bounds__(256) void lin2_kernel(
    const float* __restrict__ x,
    const float* __restrict__ Wl, const float* __restrict__ bl,
    const float* __restrict__ Wr, const float* __restrict__ br,
    float* __restrict__ xl, float* __restrict__ xr) {
  __shared__ float xs[32 * K];
  int t = threadIdx.x;
  int node0 = blockIdx.x * 32;
  for (int i = t; i < 32 * K; i += 256) xs[i] = x[node0 * K + i];
  __syncthreads();
  int cg = t & 63;        // 64 col-groups x 4 cols = 256 combined cols
  int ng = t >> 6;        // 4 node-groups x 8 nodes
  int c0 = cg * 4;
  bool isR = (c0 >= HIDC);
  const float* W    = isR ? Wr : Wl;
  const float* bias = isR ? br : bl;
  float* dst        = isR ? xr : xl;
  int wc = isR ? (c0 - HIDC) : c0;

  float4 acc[8];
  #pragma unroll
  for (int nn = 0; nn < 8; ++nn) acc[nn] = make_float4(0.f, 0.f, 0.f, 0.f);

  if constexpr (K % 4 == 0) {
    for (int k0 = 0; k0 < K; k0 += 4) {
      float4 xv[8];
      #pragma unroll
      for (int nn = 0; nn < 8; ++nn)
        xv[nn] = *(const float4*)&xs[(ng * 8 + nn) * K + k0];  // uniform-addr broadcast
      #pragma unroll
      for (int q = 0; q < 4; ++q) {
        float4 w = *(const float4*)(W + (size_t)(k0 + q) * HIDC + wc);
        #pragma unroll
        for (int nn = 0; nn < 8; ++nn) {
          float xq = (q == 0) ? xv[nn].x : (q == 1) ? xv[nn].y : (q == 2) ? xv[nn].z : xv[nn].w;
          acc[nn].x = fmaf(xq, w.x, acc[nn].x);
          acc[nn].y = fmaf(xq, w.y, acc[nn].y);
          acc[nn].z = fmaf(xq, w.z, acc[nn].z);
          acc[nn].w = fmaf(xq, w.w, acc[nn].w);
        }
      }
    }
  } else {
    for (int k = 0; k < K; ++k) {
      float4 w = *(const float4*)(W + (size_t)k * HIDC + wc);
      #pragma unroll
      for (int nn = 0; nn < 8; ++nn) {
        float xq = xs[(ng * 8 + nn) * K + k];
        acc[nn].x = fmaf(xq, w.x, acc[nn].x);
        acc[nn].y = fmaf(xq, w.y, acc[nn].y);
        acc[nn].z = fmaf(xq, w.z, acc[nn].z);
        acc[nn].w = fmaf(xq, w.w, acc[nn].w);
      }
    }
  }
  float4 b4 = *(const float4*)(bias + wc);
  #pragma unroll
  for (int nn = 0; nn < 8; ++nn) {
    int node = node0 + ng * 8 + nn;
    float4 o;
    o.x = acc[nn].x + b4.x; o.y = acc[nn].y + b4.y;
    o.z = acc[nn].z + b4.z; o.w = acc[nn].w + b4.w;
    *(float4*)(dst + (size_t)node * HIDC + wc) = o;
  }
}

// -------- GATv2 attention + aggregate + bias + relu (wave per node), optional fused final --
template<bool FINAL>
__global__ __launch_bounds__(256) void gat_attn_kernel(
    const float* __restrict__ xl, const float* __restrict__ xr,
    const int* __restrict__ knn, const float* __restrict__ att,
    const float* __restrict__ bias, float* __restrict__ xout,
    const float* __restrict__ Wf, const float* __restrict__ bf,
    float* __restrict__ out) {
  int wid = threadIdx.x >> 6;
  int lane = threadIdx.x & 63;
  int n = blockIdx.x * 4 + wid;
  int c0 = 2 * lane, c1 = 2 * lane + 1;
  float2 xr2 = *(const float2*)(xr + (size_t)n * HIDC + c0);
  float2 a2  = *(const float2*)(att + c0);
  int myj = (lane < KNB) ? knn[n * KNB + lane] : 0;
  float g0[8], g1[8], lg[8];
  #pragma unroll
  for (int k = 0; k < 8; ++k) {
    int j = __builtin_amdgcn_readlane(myj, k);
    float2 g = *(const float2*)(xl + (size_t)j * HIDC + c0);
    g0[k] = g.x; g1[k] = g.y;
    float e0 = g.x + xr2.x; e0 = (e0 > 0.f) ? e0 : 0.2f * e0;
    float e1 = g.y + xr2.y; e1 = (e1 > 0.f) ? e1 : 0.2f * e1;
    lg[k] = wave_sum(e0 * a2.x + e1 * a2.y);
  }
  float mx = lg[0];
  #pragma unroll
  for (int k = 1; k < 8; ++k) mx = fmaxf(mx, lg[k]);
  float ssum = 0.f, w[8];
  #pragma unroll
  for (int k = 0; k < 8; ++k) { w[k] = __expf(lg[k] - mx); ssum += w[k]; }
  float inv = 1.f / ssum;
  float o0 = 0.f, o1 = 0.f;
  #pragma unroll
  for (int k = 0; k < 8; ++k) { o0 += w[k] * g0[k]; o1 += w[k] * g1[k]; }
  o0 = fmaxf(fmaf(o0, inv, bias[c0]), 0.f);
  o1 = fmaxf(fmaf(o1, inv, bias[c1]), 0.f);
  if (!FINAL) {
    float2 o; o.x = o0; o.y = o1;
    *(float2*)(xout + (size_t)n * HIDC + c0) = o;
  } else {
    #pragma unroll
    for (int cls = 0; cls < 3; ++cls) {
      float p = wave_sum(o0 * Wf[c0 * 3 + cls] + o1 * Wf[c1 * 3 + cls]);
      if (lane == 0) out[n * 3 + cls] = p + bf[cls];
    }
  }
}

extern "C" void kernel_launch(void* const* d_in, const int* in_sizes, int n_in,
                              void* d_out, int out_size, void* d_ws, size_t ws_size,
                              hipStream_t stream) {
  const float* coord = (const float*)d_in[0];
  const float* feat  = (const float*)d_in[1];
  const int*   batch = (const int*)d_in[2];
  const float* Wl0 = (const float*)d_in[3];
  const float* bl0 = (const float*)d_in[4];
  const float* Wr0 = (const float*)d_in[5];
  const float* br0 = (const float*)d_in[6];
  const float* att0  = (const float*)d_in[7];
  const float* bias0 = (const float*)d_in[8];
  const float* Wl1 = (const float*)d_in[9];
  const float* bl1 = (const float*)d_in[10];
  const float* Wr1 = (const float*)d_in[11];
  const float* br1 = (const float*)d_in[12];
  const float* att1  = (const float*)d_in[13];
  const float* bias1 = (const float*)d_in[14];
  const float* Wl2 = (const float*)d_in[15];
  const float* bl2 = (const float*)d_in[16];
  const float* Wr2 = (const float*)d_in[17];
  const float* br2 = (const float*)d_in[18];
  const float* att2  = (const float*)d_in[19];
  const float* bias2 = (const float*)d_in[20];
  const float* Wf = (const float*)d_in[21];
  const float* bf = (const float*)d_in[22];
  float* out = (float*)d_out;

  char* ws = (char*)d_ws;
  int*   knn = (int*)ws;                                   // 512 KB
  float* xl  = (float*)(ws + (512 << 10));                 // 8 MB
  float* xr  = xl + (size_t)NNODES * HIDC;                 // 8 MB
  float* xb0 = xr + (size_t)NNODES * HIDC;                 // 8 MB
  float* xb1 = xb0 + (size_t)NNODES * HIDC;                // 8 MB
  int*   seg = (int*)xb0;  // 9 ints; xb0 not live until gat0 writes it

  seg_kernel<<<1, 16, 0, stream>>>(batch, seg);
  knn_kernel<<<NNODES / 8, 512, 0, stream>>>(coord, batch, seg, knn);

  lin2_kernel<6><<<NNODES / 32, 256, 0, stream>>>(feat, Wl0, bl0, Wr0, br0, xl, xr);
  gat_attn_kernel<false><<<NNODES / 4, 256, 0, stream>>>(xl, xr, knn, att0, bias0, xb0,
                                                         nullptr, nullptr, nullptr);

  lin2_kernel<128><<<NNODES / 32, 256, 0, stream>>>(xb0, Wl1, bl1, Wr1, br1, xl, xr);
  gat_attn_kernel<false><<<NNODES / 4, 256, 0, stream>>>(xl, xr, knn, att1, bias1, xb1,
                                                         nullptr, nullptr, nullptr);

  lin2_kernel<128><<<NNODES / 32, 256, 0, stream>>>(xb1, Wl2, bl2, Wr2, br2, xl, xr);
  gat_attn_kernel<true><<<NNODES / 4, 256, 0, stream>>>(xl, xr, knn, att2, bias2, nullptr,
                                                        Wf, bf, out);
}

// Round 5
// 167.016 us; speedup vs baseline: 1.0033x; 1.0033x over previous
//
#include <hip/hip_runtime.h>
#include <hip/hip_bf16.h>
#include <float.h>
#include <limits.h>

#define NNODES 16384
#define KNB 8
#define HIDC 128
#define KNN_CAP 2560   // LDS candidate window (float4 each = 40KB)

// -------- DPP helpers (pure-VALU cross-lane) --------
__device__ __forceinline__ unsigned int dpp_shr1_u32(unsigned int v) {
  // row_shr:1 (0x111); bound_ctrl=1 -> lane 0 of each 16-lane row reads 0
  // (rows 1..3 corruption at lanes 16/32/48 is harmless: list lives in lanes 0..7)
  return (unsigned int)__builtin_amdgcn_update_dpp(0, (int)v, 0x111, 0xF, 0xF, true);
}
__device__ __forceinline__ float wave_sum(float x) {
  x += __int_as_float(__builtin_amdgcn_update_dpp(0, __float_as_int(x), 0xB1, 0xF, 0xF, true));  // quad xor1
  x += __int_as_float(__builtin_amdgcn_update_dpp(0, __float_as_int(x), 0x4E, 0xF, 0xF, true));  // quad xor2
  x += __int_as_float(__builtin_amdgcn_update_dpp(0, __float_as_int(x), 0x124, 0xF, 0xF, true)); // row_ror:4
  x += __int_as_float(__builtin_amdgcn_update_dpp(0, __float_as_int(x), 0x128, 0xF, 0xF, true)); // row_ror:8
  float r0 = __int_as_float(__builtin_amdgcn_readlane(__float_as_int(x), 0));
  float r1 = __int_as_float(__builtin_amdgcn_readlane(__float_as_int(x), 16));
  float r2 = __int_as_float(__builtin_amdgcn_readlane(__float_as_int(x), 32));
  float r3 = __int_as_float(__builtin_amdgcn_readlane(__float_as_int(x), 48));
  return (r0 + r1) + (r2 + r3);
}

// squared distance — ONE formula everywhere so each (query,candidate) pair
// gets a single consistent rounding
__device__ __forceinline__ float dist2(float ax, float ay, float az,
                                       float bx, float by, float bz) {
  float dx = ax - bx, dy = ay - by, dz = az - bz;
  return fmaf(dz, dz, fmaf(dy, dy, dx * dx));
}

// Insert all survivor keys (marked in mask m) into the distributed sorted
// top-8 list (lanes 0..7 hold llo/lhi ascending). In-loop tau re-check skips
// keys made stale by earlier inserts in the same mask.
__device__ __forceinline__ void insert_survivors(
    unsigned long long m, unsigned int c_lo, unsigned int c_hi,
    unsigned int& llo, unsigned int& lhi, unsigned long long& tau) {
  while (m) {
    int src = __builtin_ctzll(m);
    m &= m - 1;
    unsigned int nlo = (unsigned int)__builtin_amdgcn_readlane((int)c_lo, src);
    unsigned int nhi = (unsigned int)__builtin_amdgcn_readlane((int)c_hi, src);
    unsigned long long nk = ((unsigned long long)nhi << 32) | nlo;
    if (nk >= tau) continue;          // stale survivor: tau tightened already
    unsigned int plo = dpp_shr1_u32(llo);
    unsigned int phi = dpp_shr1_u32(lhi);
    unsigned long long pk = ((unsigned long long)phi << 32) | plo;
    unsigned long long ck = ((unsigned long long)lhi << 32) | llo;
    if (nk < ck) {
      unsigned long long r = (pk > nk) ? pk : nk;
      llo = (unsigned int)r; lhi = (unsigned int)(r >> 32);
    }
    tau = (((unsigned long long)(unsigned int)__builtin_amdgcn_readlane((int)lhi, 7)) << 32)
          | (unsigned int)__builtin_amdgcn_readlane((int)llo, 7);
  }
}

// ---------------- segment table: seg[b] = lower_bound(batch, b), b in [0,8] ----------------
__global__ void seg_kernel(const int* __restrict__ batch, int* __restrict__ seg) {
  int b = threadIdx.x;
  if (b > 8) return;
  int lo = 0, hi = NNODES;
  while (lo < hi) { int m = (lo + hi) >> 1; if (batch[m] < b) lo = m + 1; else hi = m; }
  seg[b] = lo;
}

// ---------------- KNN ----------------
// Block = 512 threads (8 waves) = 8 consecutive query nodes sharing one LDS
// candidate window. Cold start: first 8 candidates only (8 serial inserts).
// Main loop: 256 candidates/iter (4/lane, strided -> conflict-free b128).
__global__ __launch_bounds__(512) void knn_kernel(
    const float* __restrict__ coord, const int* __restrict__ batch,
    const int* __restrict__ seg, int* __restrict__ knn) {
  __shared__ float4 tile[KNN_CAP];
  int t = threadIdx.x;
  int lane = t & 63;
  int n0 = blockIdx.x * 8;
  int n = n0 + (t >> 6);

  int b0 = batch[n0], b7 = batch[n0 + 7], bw = batch[n];
  int smin = seg[b0];
  int emax = seg[b7 + 1];
  int s_w = seg[bw];
  int e_w = seg[bw + 1];
  int win_end = min(emax, smin + KNN_CAP);
  int cnt = win_end - smin;

  // cooperative fill of candidate window
  for (int i = t; i < cnt; i += 512) {
    const float* cp = coord + (size_t)(smin + i) * 3;
    tile[i] = make_float4(cp[0], cp[1], cp[2], 0.f);
  }

  float cx = coord[n*3+0], cy = coord[n*3+1], cz = coord[n*3+2];

  unsigned long long tau = ~0ull;
  unsigned int llo = 0xFFFFFFFFu, lhi = 0xFFFFFFFFu;  // lanes 0..7: sorted keys

  // --- cold start: first 8 candidates only (global reads) ---
  {
    int j = s_w + (lane & 7);
    bool ok8 = (lane < KNB) && (j < e_w);
    float d = dist2(coord[j*3+0], coord[j*3+1], coord[j*3+2], cx, cy, cz);
    insert_survivors(__ballot(ok8), (unsigned int)j, __float_as_uint(d), llo, lhi, tau);
  }

  __syncthreads();

  // --- main loop: 256 candidates/iter, 4 strided per lane ---
  int lo_i = s_w - smin;
  int hi_i = min(e_w, win_end) - smin;
  for (int base = lo_i + KNB; base < hi_i; base += 256) {
    unsigned long long k[4];
    #pragma unroll
    for (int q = 0; q < 4; ++q) {
      int i = base + lane + 64 * q;
      bool ok = i < hi_i;
      float4 c = tile[ok ? i : lo_i];
      float d = dist2(c.x, c.y, c.z, cx, cy, cz);
      k[q] = ok ? (((unsigned long long)__float_as_uint(d) << 32) | (unsigned int)(smin + i))
                : ~0ull;
    }
    #pragma unroll
    for (int q = 0; q < 4; ++q) {
      unsigned long long m = __ballot(k[q] < tau);
      if (m) insert_survivors(m, (unsigned int)k[q], (unsigned int)(k[q] >> 32), llo, lhi, tau);
    }
  }

  // --- global tail: window overflow / graph straddle (rare) ---
  for (int base = max(s_w + KNB, win_end); base < e_w; base += 64) {
    int j = base + lane;
    bool ok = j < e_w;
    int jc = ok ? j : s_w;
    float d = dist2(coord[jc*3+0], coord[jc*3+1], coord[jc*3+2], cx, cy, cz);
    unsigned long long ckey = ok
        ? (((unsigned long long)__float_as_uint(d) << 32) | (unsigned int)j)
        : ~0ull;
    unsigned long long m = __ballot(ckey < tau);
    if (m) insert_survivors(m, (unsigned int)ckey, (unsigned int)(ckey >> 32), llo, lhi, tau);
  }
  if (lane < KNB) knn[n*KNB + lane] = (int)llo;
}

// ---------------- xl = x@Wl + bl ; xr = x@Wr + br  (fused, 32-node tiles) ----------------
template<int K>
__global__ __launch_bounds__(256) void lin2_kernel(
    const float* __restrict__ x,
    const float* __restrict__ Wl, const float* __restrict__ bl,
    const float* __restrict__ Wr, const float* __restrict__ br,
    float* __restrict__ xl, float* __restrict__ xr) {
  __shared__ float xs[32 * K];
  int t = threadIdx.x;
  int node0 = blockIdx.x * 32;
  for (int i = t; i < 32 * K; i += 256) xs[i] = x[node0 * K + i];
  __syncthreads();
  int cg = t & 63;        // 64 col-groups x 4 cols = 256 combined cols
  int ng = t >> 6;        // 4 node-groups x 8 nodes
  int c0 = cg * 4;
  bool isR = (c0 >= HIDC);
  const float* W    = isR ? Wr : Wl;
  const float* bias = isR ? br : bl;
  float* dst        = isR ? xr : xl;
  int wc = isR ? (c0 - HIDC) : c0;

  float4 acc[8];
  #pragma unroll
  for (int nn = 0; nn < 8; ++nn) acc[nn] = make_float4(0.f, 0.f, 0.f, 0.f);

  if constexpr (K % 4 == 0) {
    for (int k0 = 0; k0 < K; k0 += 4) {
      float4 xv[8];
      #pragma unroll
      for (int nn = 0; nn < 8; ++nn)
        xv[nn] = *(const float4*)&xs[(ng * 8 + nn) * K + k0];  // uniform-addr broadcast
      #pragma unroll
      for (int q = 0; q < 4; ++q) {
        float4 w = *(const float4*)(W + (size_t)(k0 + q) * HIDC + wc);
        #pragma unroll
        for (int nn = 0; nn < 8; ++nn) {
          float xq = (q == 0) ? xv[nn].x : (q == 1) ? xv[nn].y : (q == 2) ? xv[nn].z : xv[nn].w;
          acc[nn].x = fmaf(xq, w.x, acc[nn].x);
          acc[nn].y = fmaf(xq, w.y, acc[nn].y);
          acc[nn].z = fmaf(xq, w.z, acc[nn].z);
          acc[nn].w = fmaf(xq, w.w, acc[nn].w);
        }
      }
    }
  } else {
    for (int k = 0; k < K; ++k) {
      float4 w = *(const float4*)(W + (size_t)k * HIDC + wc);
      #pragma unroll
      for (int nn = 0; nn < 8; ++nn) {
        float xq = xs[(ng * 8 + nn) * K + k];
        acc[nn].x = fmaf(xq, w.x, acc[nn].x);
        acc[nn].y = fmaf(xq, w.y, acc[nn].y);
        acc[nn].z = fmaf(xq, w.z, acc[nn].z);
        acc[nn].w = fmaf(xq, w.w, acc[nn].w);
      }
    }
  }
  float4 b4 = *(const float4*)(bias + wc);
  #pragma unroll
  for (int nn = 0; nn < 8; ++nn) {
    int node = node0 + ng * 8 + nn;
    float4 o;
    o.x = acc[nn].x + b4.x; o.y = acc[nn].y + b4.y;
    o.z = acc[nn].z + b4.z; o.w = acc[nn].w + b4.w;
    *(float4*)(dst + (size_t)node * HIDC + wc) = o;
  }
}

// -------- GATv2 attention + aggregate + bias + relu (wave per node), optional fused final --
template<bool FINAL>
__global__ __launch_bounds__(256) void gat_attn_kernel(
    const float* __restrict__ xl, const float* __restrict__ xr,
    const int* __restrict__ knn, const float* __restrict__ att,
    const float* __restrict__ bias, float* __restrict__ xout,
    const float* __restrict__ Wf, const float* __restrict__ bf,
    float* __restrict__ out) {
  int wid = threadIdx.x >> 6;
  int lane = threadIdx.x & 63;
  int n = blockIdx.x * 4 + wid;
  int c0 = 2 * lane, c1 = 2 * lane + 1;
  float2 xr2 = *(const float2*)(xr + (size_t)n * HIDC + c0);
  float2 a2  = *(const float2*)(att + c0);
  int myj = (lane < KNB) ? knn[n * KNB + lane] : 0;
  float g0[8], g1[8], lg[8];
  #pragma unroll
  for (int k = 0; k < 8; ++k) {
    int j = __builtin_amdgcn_readlane(myj, k);
    float2 g = *(const float2*)(xl + (size_t)j * HIDC + c0);
    g0[k] = g.x; g1[k] = g.y;
    float e0 = g.x + xr2.x; e0 = (e0 > 0.f) ? e0 : 0.2f * e0;
    float e1 = g.y + xr2.y; e1 = (e1 > 0.f) ? e1 : 0.2f * e1;
    lg[k] = wave_sum(e0 * a2.x + e1 * a2.y);
  }
  float mx = lg[0];
  #pragma unroll
  for (int k = 1; k < 8; ++k) mx = fmaxf(mx, lg[k]);
  float ssum = 0.f, w[8];
  #pragma unroll
  for (int k = 0; k < 8; ++k) { w[k] = __expf(lg[k] - mx); ssum += w[k]; }
  float inv = 1.f / ssum;
  float o0 = 0.f, o1 = 0.f;
  #pragma unroll
  for (int k = 0; k < 8; ++k) { o0 += w[k] * g0[k]; o1 += w[k] * g1[k]; }
  o0 = fmaxf(fmaf(o0, inv, bias[c0]), 0.f);
  o1 = fmaxf(fmaf(o1, inv, bias[c1]), 0.f);
  if (!FINAL) {
    float2 o; o.x = o0; o.y = o1;
    *(float2*)(xout + (size_t)n * HIDC + c0) = o;
  } else {
    #pragma unroll
    for (int cls = 0; cls < 3; ++cls) {
      float p = wave_sum(o0 * Wf[c0 * 3 + cls] + o1 * Wf[c1 * 3 + cls]);
      if (lane == 0) out[n * 3 + cls] = p + bf[cls];
    }
  }
}

extern "C" void kernel_launch(void* const* d_in, const int* in_sizes, int n_in,
                              void* d_out, int out_size, void* d_ws, size_t ws_size,
                              hipStream_t stream) {
  const float* coord = (const float*)d_in[0];
  const float* feat  = (const float*)d_in[1];
  const int*   batch = (const int*)d_in[2];
  const float* Wl0 = (const float*)d_in[3];
  const float* bl0 = (const float*)d_in[4];
  const float* Wr0 = (const float*)d_in[5];
  const float* br0 = (const float*)d_in[6];
  const float* att0  = (const float*)d_in[7];
  const float* bias0 = (const float*)d_in[8];
  const float* Wl1 = (const float*)d_in[9];
  const float* bl1 = (const float*)d_in[10];
  const float* Wr1 = (const float*)d_in[11];
  const float* br1 = (const float*)d_in[12];
  const float* att1  = (const float*)d_in[13];
  const float* bias1 = (const float*)d_in[14];
  const float* Wl2 = (const float*)d_in[15];
  const float* bl2 = (const float*)d_in[16];
  const float* Wr2 = (const float*)d_in[17];
  const float* br2 = (const float*)d_in[18];
  const float* att2  = (const float*)d_in[19];
  const float* bias2 = (const float*)d_in[20];
  const float* Wf = (const float*)d_in[21];
  const float* bf = (const float*)d_in[22];
  float* out = (float*)d_out;

  char* ws = (char*)d_ws;
  int*   knn = (int*)ws;                                   // 512 KB
  float* xl  = (float*)(ws + (512 << 10));                 // 8 MB
  float* xr  = xl + (size_t)NNODES * HIDC;                 // 8 MB
  float* xb0 = xr + (size_t)NNODES * HIDC;                 // 8 MB
  float* xb1 = xb0 + (size_t)NNODES * HIDC;                // 8 MB
  int*   seg = (int*)xb0;  // 9 ints; xb0 not live until gat0 writes it

  seg_kernel<<<1, 16, 0, stream>>>(batch, seg);
  knn_kernel<<<NNODES / 8, 512, 0, stream>>>(coord, batch, seg, knn);

  lin2_kernel<6><<<NNODES / 32, 256, 0, stream>>>(feat, Wl0, bl0, Wr0, br0, xl, xr);
  gat_attn_kernel<false><<<NNODES / 4, 256, 0, stream>>>(xl, xr, knn, att0, bias0, xb0,
                                                         nullptr, nullptr, nullptr);

  lin2_kernel<128><<<NNODES / 32, 256, 0, stream>>>(xb0, Wl1, bl1, Wr1, br1, xl, xr);
  gat_attn_kernel<false><<<NNODES / 4, 256, 0, stream>>>(xl, xr, knn, att1, bias1, xb1,
                                                         nullptr, nullptr, nullptr);

  lin2_kernel<128><<<NNODES / 32, 256, 0, stream>>>(xb1, Wl2, bl2, Wr2, br2, xl, xr);
  gat_attn_kernel<true><<<NNODES / 4, 256, 0, stream>>>(xl, xr, knn, att2, bias2, nullptr,
                                                        Wf, bf, out);
}

// Round 6
// 152.673 us; speedup vs baseline: 1.0976x; 1.0939x over previous
//
#include <hip/hip_runtime.h>
#include <hip/hip_bf16.h>
#include <float.h>
#include <limits.h>

#define NNODES 16384
#define KNB 8
#define HIDC 128
#define KNN_CAP 2560   // LDS candidate window (float4 each = 40KB)

// -------- DPP helpers (pure-VALU cross-lane) --------
__device__ __forceinline__ float wave_sum(float x) {
  x += __int_as_float(__builtin_amdgcn_update_dpp(0, __float_as_int(x), 0xB1, 0xF, 0xF, true));  // quad xor1
  x += __int_as_float(__builtin_amdgcn_update_dpp(0, __float_as_int(x), 0x4E, 0xF, 0xF, true));  // quad xor2
  x += __int_as_float(__builtin_amdgcn_update_dpp(0, __float_as_int(x), 0x124, 0xF, 0xF, true)); // row_ror:4
  x += __int_as_float(__builtin_amdgcn_update_dpp(0, __float_as_int(x), 0x128, 0xF, 0xF, true)); // row_ror:8
  float r0 = __int_as_float(__builtin_amdgcn_readlane(__float_as_int(x), 0));
  float r1 = __int_as_float(__builtin_amdgcn_readlane(__float_as_int(x), 16));
  float r2 = __int_as_float(__builtin_amdgcn_readlane(__float_as_int(x), 32));
  float r3 = __int_as_float(__builtin_amdgcn_readlane(__float_as_int(x), 48));
  return (r0 + r1) + (r2 + r3);
}

// wave-wide min of f32 (all values finite). Rotation-only DPP: no invalid lanes.
__device__ __forceinline__ float wave_min_f32(float x) {
  x = fminf(x, __int_as_float(__builtin_amdgcn_update_dpp(0, __float_as_int(x), 0xB1, 0xF, 0xF, true)));
  x = fminf(x, __int_as_float(__builtin_amdgcn_update_dpp(0, __float_as_int(x), 0x4E, 0xF, 0xF, true)));
  x = fminf(x, __int_as_float(__builtin_amdgcn_update_dpp(0, __float_as_int(x), 0x124, 0xF, 0xF, true)));
  x = fminf(x, __int_as_float(__builtin_amdgcn_update_dpp(0, __float_as_int(x), 0x128, 0xF, 0xF, true)));
  float r0 = __int_as_float(__builtin_amdgcn_readlane(__float_as_int(x), 0));
  float r1 = __int_as_float(__builtin_amdgcn_readlane(__float_as_int(x), 16));
  float r2 = __int_as_float(__builtin_amdgcn_readlane(__float_as_int(x), 32));
  float r3 = __int_as_float(__builtin_amdgcn_readlane(__float_as_int(x), 48));
  return fminf(fminf(r0, r1), fminf(r2, r3));
}

// squared distance — ONE formula everywhere so each (query,candidate) pair
// gets a single consistent rounding
__device__ __forceinline__ float dist2(float ax, float ay, float az,
                                       float bx, float by, float bz) {
  float dx = ax - bx, dy = ay - by, dz = az - bz;
  return fmaf(dz, dz, fmaf(dy, dy, dx * dx));
}

// Branchless sorted-insert of d into ascending l0..l7 (v_med3_f32 per slot).
#define INS8(d)                                   \
  do {                                            \
    float _d = (d);                               \
    l7 = __builtin_amdgcn_fmed3f(_d, l6, l7);     \
    l6 = __builtin_amdgcn_fmed3f(_d, l5, l6);     \
    l5 = __builtin_amdgcn_fmed3f(_d, l4, l5);     \
    l4 = __builtin_amdgcn_fmed3f(_d, l3, l4);     \
    l3 = __builtin_amdgcn_fmed3f(_d, l2, l3);     \
    l2 = __builtin_amdgcn_fmed3f(_d, l1, l2);     \
    l1 = __builtin_amdgcn_fmed3f(_d, l0, l1);     \
    l0 = fminf(l0, _d);                           \
  } while (0)

// ---------------- segment table: seg[b] = lower_bound(batch, b), b in [0,8] ----------------
__global__ void seg_kernel(const int* __restrict__ batch, int* __restrict__ seg) {
  int b = threadIdx.x;
  if (b > 8) return;
  int lo = 0, hi = NNODES;
  while (lo < hi) { int m = (lo + hi) >> 1; if (batch[m] < b) lo = m + 1; else hi = m; }
  seg[b] = lo;
}

// ---------------- KNN ----------------
// Block = 512 threads (8 waves) = 8 consecutive query nodes sharing one LDS
// candidate window. Pass 1: per-lane branchless top-8 distances (med3 insert).
// Merge: 8 DPP-min pop rounds -> T = exact 8th-smallest distance.
// Pass 2: re-scan, ballot(d <= T), winners self-place via prefix rank.
// Neighbor order is free (softmax+sum over k are permutation-invariant).
__global__ __launch_bounds__(512) void knn_kernel(
    const float* __restrict__ coord, const int* __restrict__ batch,
    const int* __restrict__ seg, int* __restrict__ knn) {
  __shared__ float4 tile[KNN_CAP];
  int t = threadIdx.x;
  int lane = t & 63;
  int n0 = blockIdx.x * 8;
  int n = n0 + (t >> 6);

  int b0 = batch[n0], b7 = batch[n0 + 7], bw = batch[n];
  int smin = seg[b0];
  int emax = seg[b7 + 1];
  int s_w = seg[bw];
  int e_w = seg[bw + 1];
  int win_end = min(emax, smin + KNN_CAP);
  int cnt_fill = win_end - smin;

  // cooperative fill of candidate window
  for (int i = t; i < cnt_fill; i += 512) {
    const float* cp = coord + (size_t)(smin + i) * 3;
    tile[i] = make_float4(cp[0], cp[1], cp[2], 0.f);
  }
  __syncthreads();

  float cx = coord[n*3+0], cy = coord[n*3+1], cz = coord[n*3+2];

  // ---- pass 1: per-lane branchless top-8 distances ----
  float l0 = FLT_MAX, l1 = FLT_MAX, l2 = FLT_MAX, l3 = FLT_MAX,
        l4 = FLT_MAX, l5 = FLT_MAX, l6 = FLT_MAX, l7 = FLT_MAX;
  int lo_i = s_w - smin;
  int hi_i = min(e_w, win_end) - smin;
  #pragma unroll 2
  for (int base = lo_i; base < hi_i; base += 64) {
    int i = base + lane;
    bool ok = i < hi_i;
    float4 c = tile[ok ? i : lo_i];
    float d = dist2(c.x, c.y, c.z, cx, cy, cz);
    d = ok ? d : FLT_MAX;
    INS8(d);
  }
  // global tail (window overflow / straddle; rare)
  for (int base = max(s_w, win_end); base < e_w; base += 64) {
    int j = base + lane;
    bool ok = j < e_w;
    int jc = ok ? j : s_w;
    float d = dist2(coord[jc*3+0], coord[jc*3+1], coord[jc*3+2], cx, cy, cz);
    d = ok ? d : FLT_MAX;
    INS8(d);
  }

  // ---- merge: pop 8 wave-wide minima; T = 8th smallest ----
  float T = 0.f;
  #pragma unroll
  for (int r = 0; r < KNB; ++r) {
    float m = wave_min_f32(l0);
    T = m;
    unsigned long long msk = __ballot(l0 == m);
    int p = (int)__builtin_ctzll(msk);   // pop exactly one instance
    if (lane == p) {
      l0 = l1; l1 = l2; l2 = l3; l3 = l4; l4 = l5; l5 = l6; l6 = l7; l7 = FLT_MAX;
    }
  }

  // ---- pass 2: collect indices with d <= T (count is exactly 8 generically) ----
  int cnt = 0;
  for (int base = lo_i; base < hi_i; base += 64) {
    int i = base + lane;
    bool ok = i < hi_i;
    float4 c = tile[ok ? i : lo_i];
    float d = dist2(c.x, c.y, c.z, cx, cy, cz);
    bool win = ok && (d <= T);
    unsigned long long msk = __ballot(win);
    if (msk) {
      int rank = __popcll(msk & ((1ull << lane) - 1ull));
      int slot = cnt + rank;
      if (win && slot < KNB) knn[n*KNB + slot] = smin + i;
      cnt += __popcll(msk);
    }
  }
  for (int base = max(s_w, win_end); base < e_w; base += 64) {
    int j = base + lane;
    bool ok = j < e_w;
    int jc = ok ? j : s_w;
    float d = dist2(coord[jc*3+0], coord[jc*3+1], coord[jc*3+2], cx, cy, cz);
    bool win = ok && (d <= T);
    unsigned long long msk = __ballot(win);
    if (msk) {
      int rank = __popcll(msk & ((1ull << lane) - 1ull));
      int slot = cnt + rank;
      if (win && slot < KNB) knn[n*KNB + slot] = j;
      cnt += __popcll(msk);
    }
  }
}

// ---------------- xl = x@Wl + bl ; xr = x@Wr + br  (fused, 32-node tiles) ----------------
template<int K>
__global__ __launch_bounds__(256) void lin2_kernel(
    const float* __restrict__ x,
    const float* __restrict__ Wl, const float* __restrict__ bl,
    const float* __restrict__ Wr, const float* __restrict__ br,
    float* __restrict__ xl, float* __restrict__ xr) {
  __shared__ float xs[32 * K];
  int t = threadIdx.x;
  int node0 = blockIdx.x * 32;
  for (int i = t; i < 32 * K; i += 256) xs[i] = x[node0 * K + i];
  __syncthreads();
  int cg = t & 63;        // 64 col-groups x 4 cols = 256 combined cols
  int ng = t >> 6;        // 4 node-groups x 8 nodes
  int c0 = cg * 4;
  bool isR = (c0 >= HIDC);
  const float* W    = isR ? Wr : Wl;
  const float* bias = isR ? br : bl;
  float* dst        = isR ? xr : xl;
  int wc = isR ? (c0 - HIDC) : c0;

  float4 acc[8];
  #pragma unroll
  for (int nn = 0; nn < 8; ++nn) acc[nn] = make_float4(0.f, 0.f, 0.f, 0.f);

  if constexpr (K % 4 == 0) {
    for (int k0 = 0; k0 < K; k0 += 4) {
      float4 xv[8];
      #pragma unroll
      for (int nn = 0; nn < 8; ++nn)
        xv[nn] = *(const float4*)&xs[(ng * 8 + nn) * K + k0];  // uniform-addr broadcast
      #pragma unroll
      for (int q = 0; q < 4; ++q) {
        float4 w = *(const float4*)(W + (size_t)(k0 + q) * HIDC + wc);
        #pragma unroll
        for (int nn = 0; nn < 8; ++nn) {
          float xq = (q == 0) ? xv[nn].x : (q == 1) ? xv[nn].y : (q == 2) ? xv[nn].z : xv[nn].w;
          acc[nn].x = fmaf(xq, w.x, acc[nn].x);
          acc[nn].y = fmaf(xq, w.y, acc[nn].y);
          acc[nn].z = fmaf(xq, w.z, acc[nn].z);
          acc[nn].w = fmaf(xq, w.w, acc[nn].w);
        }
      }
    }
  } else {
    for (int k = 0; k < K; ++k) {
      float4 w = *(const float4*)(W + (size_t)k * HIDC + wc);
      #pragma unroll
      for (int nn = 0; nn < 8; ++nn) {
        float xq = xs[(ng * 8 + nn) * K + k];
        acc[nn].x = fmaf(xq, w.x, acc[nn].x);
        acc[nn].y = fmaf(xq, w.y, acc[nn].y);
        acc[nn].z = fmaf(xq, w.z, acc[nn].z);
        acc[nn].w = fmaf(xq, w.w, acc[nn].w);
      }
    }
  }
  float4 b4 = *(const float4*)(bias + wc);
  #pragma unroll
  for (int nn = 0; nn < 8; ++nn) {
    int node = node0 + ng * 8 + nn;
    float4 o;
    o.x = acc[nn].x + b4.x; o.y = acc[nn].y + b4.y;
    o.z = acc[nn].z + b4.z; o.w = acc[nn].w + b4.w;
    *(float4*)(dst + (size_t)node * HIDC + wc) = o;
  }
}

// -------- GATv2 attention + aggregate + bias + relu (wave per node), optional fused final --
template<bool FINAL>
__global__ __launch_bounds__(256) void gat_attn_kernel(
    const float* __restrict__ xl, const float* __restrict__ xr,
    const int* __restrict__ knn, const float* __restrict__ att,
    const float* __restrict__ bias, float* __restrict__ xout,
    const float* __restrict__ Wf, const float* __restrict__ bf,
    float* __restrict__ out) {
  int wid = threadIdx.x >> 6;
  int lane = threadIdx.x & 63;
  int n = blockIdx.x * 4 + wid;
  int c0 = 2 * lane, c1 = 2 * lane + 1;
  float2 xr2 = *(const float2*)(xr + (size_t)n * HIDC + c0);
  float2 a2  = *(const float2*)(att + c0);
  int myj = (lane < KNB) ? knn[n * KNB + lane] : 0;
  float g0[8], g1[8], lg[8];
  #pragma unroll
  for (int k = 0; k < 8; ++k) {
    int j = __builtin_amdgcn_readlane(myj, k);
    float2 g = *(const float2*)(xl + (size_t)j * HIDC + c0);
    g0[k] = g.x; g1[k] = g.y;
    float e0 = g.x + xr2.x; e0 = (e0 > 0.f) ? e0 : 0.2f * e0;
    float e1 = g.y + xr2.y; e1 = (e1 > 0.f) ? e1 : 0.2f * e1;
    lg[k] = wave_sum(e0 * a2.x + e1 * a2.y);
  }
  float mx = lg[0];
  #pragma unroll
  for (int k = 1; k < 8; ++k) mx = fmaxf(mx, lg[k]);
  float ssum = 0.f, w[8];
  #pragma unroll
  for (int k = 0; k < 8; ++k) { w[k] = __expf(lg[k] - mx); ssum += w[k]; }
  float inv = 1.f / ssum;
  float o0 = 0.f, o1 = 0.f;
  #pragma unroll
  for (int k = 0; k < 8; ++k) { o0 += w[k] * g0[k]; o1 += w[k] * g1[k]; }
  o0 = fmaxf(fmaf(o0, inv, bias[c0]), 0.f);
  o1 = fmaxf(fmaf(o1, inv, bias[c1]), 0.f);
  if (!FINAL) {
    float2 o; o.x = o0; o.y = o1;
    *(float2*)(xout + (size_t)n * HIDC + c0) = o;
  } else {
    #pragma unroll
    for (int cls = 0; cls < 3; ++cls) {
      float p = wave_sum(o0 * Wf[c0 * 3 + cls] + o1 * Wf[c1 * 3 + cls]);
      if (lane == 0) out[n * 3 + cls] = p + bf[cls];
    }
  }
}

extern "C" void kernel_launch(void* const* d_in, const int* in_sizes, int n_in,
                              void* d_out, int out_size, void* d_ws, size_t ws_size,
                              hipStream_t stream) {
  const float* coord = (const float*)d_in[0];
  const float* feat  = (const float*)d_in[1];
  const int*   batch = (const int*)d_in[2];
  const float* Wl0 = (const float*)d_in[3];
  const float* bl0 = (const float*)d_in[4];
  const float* Wr0 = (const float*)d_in[5];
  const float* br0 = (const float*)d_in[6];
  const float* att0  = (const float*)d_in[7];
  const float* bias0 = (const float*)d_in[8];
  const float* Wl1 = (const float*)d_in[9];
  const float* bl1 = (const float*)d_in[10];
  const float* Wr1 = (const float*)d_in[11];
  const float* br1 = (const float*)d_in[12];
  const float* att1  = (const float*)d_in[13];
  const float* bias1 = (const float*)d_in[14];
  const float* Wl2 = (const float*)d_in[15];
  const float* bl2 = (const float*)d_in[16];
  const float* Wr2 = (const float*)d_in[17];
  const float* br2 = (const float*)d_in[18];
  const float* att2  = (const float*)d_in[19];
  const float* bias2 = (const float*)d_in[20];
  const float* Wf = (const float*)d_in[21];
  const float* bf = (const float*)d_in[22];
  float* out = (float*)d_out;

  char* ws = (char*)d_ws;
  int*   knn = (int*)ws;                                   // 512 KB
  float* xl  = (float*)(ws + (512 << 10));                 // 8 MB
  float* xr  = xl + (size_t)NNODES * HIDC;                 // 8 MB
  float* xb0 = xr + (size_t)NNODES * HIDC;                 // 8 MB
  float* xb1 = xb0 + (size_t)NNODES * HIDC;                // 8 MB
  int*   seg = (int*)xb0;  // 9 ints; xb0 not live until gat0 writes it

  seg_kernel<<<1, 16, 0, stream>>>(batch, seg);
  knn_kernel<<<NNODES / 8, 512, 0, stream>>>(coord, batch, seg, knn);

  lin2_kernel<6><<<NNODES / 32, 256, 0, stream>>>(feat, Wl0, bl0, Wr0, br0, xl, xr);
  gat_attn_kernel<false><<<NNODES / 4, 256, 0, stream>>>(xl, xr, knn, att0, bias0, xb0,
                                                         nullptr, nullptr, nullptr);

  lin2_kernel<128><<<NNODES / 32, 256, 0, stream>>>(xb0, Wl1, bl1, Wr1, br1, xl, xr);
  gat_attn_kernel<false><<<NNODES / 4, 256, 0, stream>>>(xl, xr, knn, att1, bias1, xb1,
                                                         nullptr, nullptr, nullptr);

  lin2_kernel<128><<<NNODES / 32, 256, 0, stream>>>(xb1, Wl2, bl2, Wr2, br2, xl, xr);
  gat_attn_kernel<true><<<NNODES / 4, 256, 0, stream>>>(xl, xr, knn, att2, bias2, nullptr,
                                                        Wf, bf, out);
}

// Round 7
// 144.636 us; speedup vs baseline: 1.1586x; 1.0556x over previous
//
#include <hip/hip_runtime.h>
#include <hip/hip_bf16.h>
#include <float.h>
#include <limits.h>

#define NNODES 16384
#define KNB 8
#define HIDC 128
#define KNN_CAP 2528   // LDS candidate window (float4 = 40448 B) -> 4 blocks/CU

// -------- DPP helpers (pure-VALU cross-lane) --------
__device__ __forceinline__ float wave_sum(float x) {
  x += __int_as_float(__builtin_amdgcn_update_dpp(0, __float_as_int(x), 0xB1, 0xF, 0xF, true));  // quad xor1
  x += __int_as_float(__builtin_amdgcn_update_dpp(0, __float_as_int(x), 0x4E, 0xF, 0xF, true));  // quad xor2
  x += __int_as_float(__builtin_amdgcn_update_dpp(0, __float_as_int(x), 0x124, 0xF, 0xF, true)); // row_ror:4
  x += __int_as_float(__builtin_amdgcn_update_dpp(0, __float_as_int(x), 0x128, 0xF, 0xF, true)); // row_ror:8
  float r0 = __int_as_float(__builtin_amdgcn_readlane(__float_as_int(x), 0));
  float r1 = __int_as_float(__builtin_amdgcn_readlane(__float_as_int(x), 16));
  float r2 = __int_as_float(__builtin_amdgcn_readlane(__float_as_int(x), 32));
  float r3 = __int_as_float(__builtin_amdgcn_readlane(__float_as_int(x), 48));
  return (r0 + r1) + (r2 + r3);
}

// wave-wide min of f32 (all values finite). Rotation-only DPP: no invalid lanes.
__device__ __forceinline__ float wave_min_f32(float x) {
  x = fminf(x, __int_as_float(__builtin_amdgcn_update_dpp(0, __float_as_int(x), 0xB1, 0xF, 0xF, true)));
  x = fminf(x, __int_as_float(__builtin_amdgcn_update_dpp(0, __float_as_int(x), 0x4E, 0xF, 0xF, true)));
  x = fminf(x, __int_as_float(__builtin_amdgcn_update_dpp(0, __float_as_int(x), 0x124, 0xF, 0xF, true)));
  x = fminf(x, __int_as_float(__builtin_amdgcn_update_dpp(0, __float_as_int(x), 0x128, 0xF, 0xF, true)));
  float r0 = __int_as_float(__builtin_amdgcn_readlane(__float_as_int(x), 0));
  float r1 = __int_as_float(__builtin_amdgcn_readlane(__float_as_int(x), 16));
  float r2 = __int_as_float(__builtin_amdgcn_readlane(__float_as_int(x), 32));
  float r3 = __int_as_float(__builtin_amdgcn_readlane(__float_as_int(x), 48));
  return fminf(fminf(r0, r1), fminf(r2, r3));
}

// squared distance — ONE formula everywhere so each (query,candidate) pair
// gets a single consistent rounding
__device__ __forceinline__ float dist2(float ax, float ay, float az,
                                       float bx, float by, float bz) {
  float dx = ax - bx, dy = ay - by, dz = az - bz;
  return fmaf(dz, dz, fmaf(dy, dy, dx * dx));
}

// Branchless sorted-insert of _d into ascending a0..a7 (v_med3_f32 per slot).
#define INS8V(_d, a0, a1, a2, a3, a4, a5, a6, a7)  \
  do {                                             \
    a7 = __builtin_amdgcn_fmed3f(_d, a6, a7);      \
    a6 = __builtin_amdgcn_fmed3f(_d, a5, a6);      \
    a5 = __builtin_amdgcn_fmed3f(_d, a4, a5);      \
    a4 = __builtin_amdgcn_fmed3f(_d, a3, a4);      \
    a3 = __builtin_amdgcn_fmed3f(_d, a2, a3);      \
    a2 = __builtin_amdgcn_fmed3f(_d, a1, a2);      \
    a1 = __builtin_amdgcn_fmed3f(_d, a0, a1);      \
    a0 = fminf(a0, _d);                            \
  } while (0)

// pop 8 wave-wide minima from the distributed lists; returns the 8th smallest
__device__ __forceinline__ float merge_T(float l0, float l1, float l2, float l3,
                                         float l4, float l5, float l6, float l7,
                                         int lane) {
  float T = 0.f;
  #pragma unroll
  for (int r = 0; r < KNB; ++r) {
    float m = wave_min_f32(l0);
    T = m;
    unsigned long long msk = __ballot(l0 == m);
    int p = (int)__builtin_ctzll(msk);
    if (lane == p) { l0 = l1; l1 = l2; l2 = l3; l3 = l4; l4 = l5; l5 = l6; l6 = l7; l7 = FLT_MAX; }
  }
  return T;
}

// slow path: exact single-query KNN over a global range (rare: graph straddle
// or window overflow). Whole wave participates.
__device__ void knn_global_single(const float* __restrict__ coord,
                                  float qx, float qy, float qz,
                                  int s, int e, int lane,
                                  int* __restrict__ knn_row) {
  float l0 = FLT_MAX, l1 = FLT_MAX, l2 = FLT_MAX, l3 = FLT_MAX,
        l4 = FLT_MAX, l5 = FLT_MAX, l6 = FLT_MAX, l7 = FLT_MAX;
  for (int base = s; base < e; base += 64) {
    int j = base + lane;
    bool ok = j < e;
    int jc = ok ? j : s;
    float d = dist2(coord[jc*3+0], coord[jc*3+1], coord[jc*3+2], qx, qy, qz);
    d = ok ? d : FLT_MAX;
    INS8V(d, l0, l1, l2, l3, l4, l5, l6, l7);
  }
  float T = merge_T(l0, l1, l2, l3, l4, l5, l6, l7, lane);
  unsigned long long lt = (1ull << lane) - 1ull;
  int cnt = 0;
  for (int base = s; base < e; base += 64) {
    int j = base + lane;
    bool ok = j < e;
    int jc = ok ? j : s;
    float d = dist2(coord[jc*3+0], coord[jc*3+1], coord[jc*3+2], qx, qy, qz);
    bool win = ok && (d <= T);
    unsigned long long msk = __ballot(win);
    if (msk) {
      int slot = cnt + __popcll(msk & lt);
      if (win && slot < KNB) knn_row[slot] = j;
      cnt += __popcll(msk);
    }
  }
}

// ---------------- KNN (+ fused seg table + fused layer-0 linear) ----------------
// Block = 512 threads (8 waves) = 16 consecutive query nodes sharing one LDS
// candidate window; each wave handles TWO queries (one tile read serves both).
__global__ __launch_bounds__(512) void knnlin_kernel(
    const float* __restrict__ coord, const int* __restrict__ batch,
    const float* __restrict__ feat,
    const float* __restrict__ Wl0, const float* __restrict__ bl0,
    const float* __restrict__ Wr0, const float* __restrict__ br0,
    int* __restrict__ knn, float* __restrict__ xl, float* __restrict__ xr) {
  __shared__ float4 tile[KNN_CAP];
  __shared__ int segs[9];
  int t = threadIdx.x;
  int lane = t & 63;
  int wid = t >> 6;
  int n0 = blockIdx.x * 16;

  // per-block segment table (9 parallel binary searches)
  if (t < 9) {
    int lo = 0, hi = NNODES;
    while (lo < hi) { int m = (lo + hi) >> 1; if (batch[m] < t) lo = m + 1; else hi = m; }
    segs[t] = lo;
  }
  __syncthreads();

  int b0 = batch[n0];
  int blast = batch[n0 + 15];
  int smin = segs[b0];
  int emax = segs[blast + 1];
  int win_end = min(emax, smin + KNN_CAP);
  int cnt_fill = win_end - smin;

  // cooperative fill of candidate window
  for (int i = t; i < cnt_fill; i += 512) {
    const float* cp = coord + (size_t)(smin + i) * 3;
    tile[i] = make_float4(cp[0], cp[1], cp[2], 0.f);
  }
  __syncthreads();

  int nA = n0 + wid * 2, nB = nA + 1;
  int bA = batch[nA], bB = batch[nB];
  int sA = segs[bA], eA = segs[bA + 1];
  bool fast = (bA == bB) && (eA - smin <= KNN_CAP);

  float ax = coord[nA*3+0], ay = coord[nA*3+1], az = coord[nA*3+2];
  float bx = coord[nB*3+0], by = coord[nB*3+1], bz = coord[nB*3+2];

  if (fast) {
    int lo_i = sA - smin;
    int M = eA - sA;
    int F = M >> 6, R = M & 63;

    // ---- pass 1: per-lane branchless top-8 distances, both queries ----
    float a0 = FLT_MAX, a1 = FLT_MAX, a2 = FLT_MAX, a3 = FLT_MAX,
          a4 = FLT_MAX, a5 = FLT_MAX, a6 = FLT_MAX, a7 = FLT_MAX;
    float b0r = FLT_MAX, b1 = FLT_MAX, b2 = FLT_MAX, b3 = FLT_MAX,
          b4 = FLT_MAX, b5 = FLT_MAX, b6 = FLT_MAX, b7 = FLT_MAX;
    const float4* tl = tile + lo_i;
    #pragma unroll 4
    for (int it = 0; it < F; ++it) {
      float4 c = tl[lane];
      tl += 64;
      float dA = dist2(c.x, c.y, c.z, ax, ay, az);
      float dB = dist2(c.x, c.y, c.z, bx, by, bz);
      INS8V(dA, a0, a1, a2, a3, a4, a5, a6, a7);
      INS8V(dB, b0r, b1, b2, b3, b4, b5, b6, b7);
    }
    if (R) {
      int i = lo_i + F * 64 + lane;
      bool ok = (F * 64 + lane) < M;
      float4 c = tile[ok ? i : lo_i];
      float dA = dist2(c.x, c.y, c.z, ax, ay, az);
      float dB = dist2(c.x, c.y, c.z, bx, by, bz);
      dA = ok ? dA : FLT_MAX;
      dB = ok ? dB : FLT_MAX;
      INS8V(dA, a0, a1, a2, a3, a4, a5, a6, a7);
      INS8V(dB, b0r, b1, b2, b3, b4, b5, b6, b7);
    }

    // ---- merge: exact 8th-smallest per query ----
    float TA = merge_T(a0, a1, a2, a3, a4, a5, a6, a7, lane);
    float TB = merge_T(b0r, b1, b2, b3, b4, b5, b6, b7, lane);

    // ---- pass 2: collect indices (first 8 by index order among d <= T) ----
    unsigned long long lt = (1ull << lane) - 1ull;
    int cntA = 0, cntB = 0;
    const float4* tl2 = tile + lo_i;
    for (int it = 0; it < F; ++it) {
      float4 c = tl2[lane];
      tl2 += 64;
      float dA = dist2(c.x, c.y, c.z, ax, ay, az);
      float dB = dist2(c.x, c.y, c.z, bx, by, bz);
      int gidx = sA + it * 64 + lane;
      unsigned long long mA = __ballot(dA <= TA);
      if (mA) {
        int slot = cntA + __popcll(mA & lt);
        if ((dA <= TA) && slot < KNB) knn[nA*KNB + slot] = gidx;
        cntA += __popcll(mA);
      }
      unsigned long long mB = __ballot(dB <= TB);
      if (mB) {
        int slot = cntB + __popcll(mB & lt);
        if ((dB <= TB) && slot < KNB) knn[nB*KNB + slot] = gidx;
        cntB += __popcll(mB);
      }
    }
    if (R) {
      int li = F * 64 + lane;
      bool ok = li < M;
      float4 c = tile[ok ? (lo_i + li) : lo_i];
      float dA = dist2(c.x, c.y, c.z, ax, ay, az);
      float dB = dist2(c.x, c.y, c.z, bx, by, bz);
      int gidx = sA + li;
      bool wA = ok && (dA <= TA);
      bool wB = ok && (dB <= TB);
      unsigned long long mA = __ballot(wA);
      if (mA) {
        int slot = cntA + __popcll(mA & lt);
        if (wA && slot < KNB) knn[nA*KNB + slot] = gidx;
        cntA += __popcll(mA);
      }
      unsigned long long mB = __ballot(wB);
      if (mB) {
        int slot = cntB + __popcll(mB & lt);
        if (wB && slot < KNB) knn[nB*KNB + slot] = gidx;
        cntB += __popcll(mB);
      }
    }
  } else {
    // rare: graph straddle / window overflow — global exact scan per query
    int sB2 = segs[bB], eB2 = segs[bB + 1];
    knn_global_single(coord, ax, ay, az, sA, eA, lane, knn + (size_t)nA * KNB);
    knn_global_single(coord, bx, by, bz, sB2, eB2, lane, knn + (size_t)nB * KNB);
  }

  // ---- fused layer-0 linear: xl/xr = feat @ Wl0/Wr0 + b for this block's 16 nodes ----
  {
    int cg = t & 63;                 // 64 col-groups of 4 (0..31 -> xl, 32..63 -> xr)
    bool isR = cg >= 32;
    const float* W  = isR ? Wr0 : Wl0;
    const float* bi = isR ? br0 : bl0;
    float* dst      = isR ? xr : xl;
    int wc = (cg & 31) * 4;
    float4 w0 = *(const float4*)(W + 0 * HIDC + wc);
    float4 w1 = *(const float4*)(W + 1 * HIDC + wc);
    float4 w2 = *(const float4*)(W + 2 * HIDC + wc);
    float4 w3 = *(const float4*)(W + 3 * HIDC + wc);
    float4 w4 = *(const float4*)(W + 4 * HIDC + wc);
    float4 w5 = *(const float4*)(W + 5 * HIDC + wc);
    float4 bb = *(const float4*)(bi + wc);
    #pragma unroll
    for (int s2 = 0; s2 < 2; ++s2) {
      int node = n0 + wid * 2 + s2;
      const float* fr = feat + (size_t)node * 6;
      float f0 = fr[0], f1 = fr[1], f2 = fr[2], f3 = fr[3], f4 = fr[4], f5 = fr[5];
      float4 acc = make_float4(0.f, 0.f, 0.f, 0.f);
      acc.x = fmaf(f0, w0.x, acc.x); acc.y = fmaf(f0, w0.y, acc.y);
      acc.z = fmaf(f0, w0.z, acc.z); acc.w = fmaf(f0, w0.w, acc.w);
      acc.x = fmaf(f1, w1.x, acc.x); acc.y = fmaf(f1, w1.y, acc.y);
      acc.z = fmaf(f1, w1.z, acc.z); acc.w = fmaf(f1, w1.w, acc.w);
      acc.x = fmaf(f2, w2.x, acc.x); acc.y = fmaf(f2, w2.y, acc.y);
      acc.z = fmaf(f2, w2.z, acc.z); acc.w = fmaf(f2, w2.w, acc.w);
      acc.x = fmaf(f3, w3.x, acc.x); acc.y = fmaf(f3, w3.y, acc.y);
      acc.z = fmaf(f3, w3.z, acc.z); acc.w = fmaf(f3, w3.w, acc.w);
      acc.x = fmaf(f4, w4.x, acc.x); acc.y = fmaf(f4, w4.y, acc.y);
      acc.z = fmaf(f4, w4.z, acc.z); acc.w = fmaf(f4, w4.w, acc.w);
      acc.x = fmaf(f5, w5.x, acc.x); acc.y = fmaf(f5, w5.y, acc.y);
      acc.z = fmaf(f5, w5.z, acc.z); acc.w = fmaf(f5, w5.w, acc.w);
      float4 o;
      o.x = acc.x + bb.x; o.y = acc.y + bb.y;
      o.z = acc.z + bb.z; o.w = acc.w + bb.w;
      *(float4*)(dst + (size_t)node * HIDC + wc) = o;
    }
  }
}

// ---------------- xl = x@Wl + bl ; xr = x@Wr + br  (fused, 32-node tiles) ----------------
template<int K>
__global__ __launch_bounds__(256) void lin2_kernel(
    const float* __restrict__ x,
    const float* __restrict__ Wl, const float* __restrict__ bl,
    const float* __restrict__ Wr, const float* __restrict__ br,
    float* __restrict__ xl, float* __restrict__ xr) {
  __shared__ float xs[32 * K];
  int t = threadIdx.x;
  int node0 = blockIdx.x * 32;
  for (int i = t; i < 32 * K; i += 256) xs[i] = x[node0 * K + i];
  __syncthreads();
  int cg = t & 63;        // 64 col-groups x 4 cols = 256 combined cols
  int ng = t >> 6;        // 4 node-groups x 8 nodes
  int c0 = cg * 4;
  bool isR = (c0 >= HIDC);
  const float* W    = isR ? Wr : Wl;
  const float* bias = isR ? br : bl;
  float* dst        = isR ? xr : xl;
  int wc = isR ? (c0 - HIDC) : c0;

  float4 acc[8];
  #pragma unroll
  for (int nn = 0; nn < 8; ++nn) acc[nn] = make_float4(0.f, 0.f, 0.f, 0.f);

  for (int k0 = 0; k0 < K; k0 += 4) {
    float4 xv[8];
    #pragma unroll
    for (int nn = 0; nn < 8; ++nn)
      xv[nn] = *(const float4*)&xs[(ng * 8 + nn) * K + k0];  // uniform-addr broadcast
    #pragma unroll
    for (int q = 0; q < 4; ++q) {
      float4 w = *(const float4*)(W + (size_t)(k0 + q) * HIDC + wc);
      #pragma unroll
      for (int nn = 0; nn < 8; ++nn) {
        float xq = (q == 0) ? xv[nn].x : (q == 1) ? xv[nn].y : (q == 2) ? xv[nn].z : xv[nn].w;
        acc[nn].x = fmaf(xq, w.x, acc[nn].x);
        acc[nn].y = fmaf(xq, w.y, acc[nn].y);
        acc[nn].z = fmaf(xq, w.z, acc[nn].z);
        acc[nn].w = fmaf(xq, w.w, acc[nn].w);
      }
    }
  }
  float4 b4 = *(const float4*)(bias + wc);
  #pragma unroll
  for (int nn = 0; nn < 8; ++nn) {
    int node = node0 + ng * 8 + nn;
    float4 o;
    o.x = acc[nn].x + b4.x; o.y = acc[nn].y + b4.y;
    o.z = acc[nn].z + b4.z; o.w = acc[nn].w + b4.w;
    *(float4*)(dst + (size_t)node * HIDC + wc) = o;
  }
}

// -------- GATv2 attention + aggregate + bias + relu (wave per node), optional fused final --
template<bool FINAL>
__global__ __launch_bounds__(256) void gat_attn_kernel(
    const float* __restrict__ xl, const float* __restrict__ xr,
    const int* __restrict__ knn, const float* __restrict__ att,
    const float* __restrict__ bias, float* __restrict__ xout,
    const float* __restrict__ Wf, const float* __restrict__ bf,
    float* __restrict__ out) {
  int wid = threadIdx.x >> 6;
  int lane = threadIdx.x & 63;
  int n = blockIdx.x * 4 + wid;
  int c0 = 2 * lane, c1 = 2 * lane + 1;
  float2 xr2 = *(const float2*)(xr + (size_t)n * HIDC + c0);
  float2 a2  = *(const float2*)(att + c0);
  int myj = (lane < KNB) ? knn[n * KNB + lane] : 0;
  float g0[8], g1[8], lg[8];
  #pragma unroll
  for (int k = 0; k < 8; ++k) {
    int j = __builtin_amdgcn_readlane(myj, k);
    float2 g = *(const float2*)(xl + (size_t)j * HIDC + c0);
    g0[k] = g.x; g1[k] = g.y;
    float e0 = g.x + xr2.x; e0 = (e0 > 0.f) ? e0 : 0.2f * e0;
    float e1 = g.y + xr2.y; e1 = (e1 > 0.f) ? e1 : 0.2f * e1;
    lg[k] = wave_sum(e0 * a2.x + e1 * a2.y);
  }
  float mx = lg[0];
  #pragma unroll
  for (int k = 1; k < 8; ++k) mx = fmaxf(mx, lg[k]);
  float ssum = 0.f, w[8];
  #pragma unroll
  for (int k = 0; k < 8; ++k) { w[k] = __expf(lg[k] - mx); ssum += w[k]; }
  float inv = 1.f / ssum;
  float o0 = 0.f, o1 = 0.f;
  #pragma unroll
  for (int k = 0; k < 8; ++k) { o0 += w[k] * g0[k]; o1 += w[k] * g1[k]; }
  o0 = fmaxf(fmaf(o0, inv, bias[c0]), 0.f);
  o1 = fmaxf(fmaf(o1, inv, bias[c1]), 0.f);
  if (!FINAL) {
    float2 o; o.x = o0; o.y = o1;
    *(float2*)(xout + (size_t)n * HIDC + c0) = o;
  } else {
    #pragma unroll
    for (int cls = 0; cls < 3; ++cls) {
      float p = wave_sum(o0 * Wf[c0 * 3 + cls] + o1 * Wf[c1 * 3 + cls]);
      if (lane == 0) out[n * 3 + cls] = p + bf[cls];
    }
  }
}

extern "C" void kernel_launch(void* const* d_in, const int* in_sizes, int n_in,
                              void* d_out, int out_size, void* d_ws, size_t ws_size,
                              hipStream_t stream) {
  const float* coord = (const float*)d_in[0];
  const float* feat  = (const float*)d_in[1];
  const int*   batch = (const int*)d_in[2];
  const float* Wl0 = (const float*)d_in[3];
  const float* bl0 = (const float*)d_in[4];
  const float* Wr0 = (const float*)d_in[5];
  const float* br0 = (const float*)d_in[6];
  const float* att0  = (const float*)d_in[7];
  const float* bias0 = (const float*)d_in[8];
  const float* Wl1 = (const float*)d_in[9];
  const float* bl1 = (const float*)d_in[10];
  const float* Wr1 = (const float*)d_in[11];
  const float* br1 = (const float*)d_in[12];
  const float* att1  = (const float*)d_in[13];
  const float* bias1 = (const float*)d_in[14];
  const float* Wl2 = (const float*)d_in[15];
  const float* bl2 = (const float*)d_in[16];
  const float* Wr2 = (const float*)d_in[17];
  const float* br2 = (const float*)d_in[18];
  const float* att2  = (const float*)d_in[19];
  const float* bias2 = (const float*)d_in[20];
  const float* Wf = (const float*)d_in[21];
  const float* bf = (const float*)d_in[22];
  float* out = (float*)d_out;

  char* ws = (char*)d_ws;
  int*   knn = (int*)ws;                                   // 512 KB
  float* xl  = (float*)(ws + (512 << 10));                 // 8 MB
  float* xr  = xl + (size_t)NNODES * HIDC;                 // 8 MB
  float* xb0 = xr + (size_t)NNODES * HIDC;                 // 8 MB
  float* xb1 = xb0 + (size_t)NNODES * HIDC;                // 8 MB

  knnlin_kernel<<<NNODES / 16, 512, 0, stream>>>(coord, batch, feat,
                                                 Wl0, bl0, Wr0, br0, knn, xl, xr);
  gat_attn_kernel<false><<<NNODES / 4, 256, 0, stream>>>(xl, xr, knn, att0, bias0, xb0,
                                                         nullptr, nullptr, nullptr);

  lin2_kernel<128><<<NNODES / 32, 256, 0, stream>>>(xb0, Wl1, bl1, Wr1, br1, xl, xr);
  gat_attn_kernel<false><<<NNODES / 4, 256, 0, stream>>>(xl, xr, knn, att1, bias1, xb1,
                                                         nullptr, nullptr, nullptr);

  lin2_kernel<128><<<NNODES / 32, 256, 0, stream>>>(xb1, Wl2, bl2, Wr2, br2, xl, xr);
  gat_attn_kernel<true><<<NNODES / 4, 256, 0, stream>>>(xl, xr, knn, att2, bias2, nullptr,
                                                        Wf, bf, out);
}

// Round 8
// 142.053 us; speedup vs baseline: 1.1796x; 1.0182x over previous
//
#include <hip/hip_runtime.h>
#include <hip/hip_bf16.h>
#include <float.h>
#include <limits.h>

#define NNODES 16384
#define KNB 8
#define HIDC 128
#define KNN_CAP 2528   // LDS candidate window (float4 = 40448 B) -> 4 blocks/CU

// -------- DPP helpers (pure-VALU cross-lane) --------
__device__ __forceinline__ float wave_sum(float x) {
  x += __int_as_float(__builtin_amdgcn_update_dpp(0, __float_as_int(x), 0xB1, 0xF, 0xF, true));  // quad xor1
  x += __int_as_float(__builtin_amdgcn_update_dpp(0, __float_as_int(x), 0x4E, 0xF, 0xF, true));  // quad xor2
  x += __int_as_float(__builtin_amdgcn_update_dpp(0, __float_as_int(x), 0x124, 0xF, 0xF, true)); // row_ror:4
  x += __int_as_float(__builtin_amdgcn_update_dpp(0, __float_as_int(x), 0x128, 0xF, 0xF, true)); // row_ror:8
  float r0 = __int_as_float(__builtin_amdgcn_readlane(__float_as_int(x), 0));
  float r1 = __int_as_float(__builtin_amdgcn_readlane(__float_as_int(x), 16));
  float r2 = __int_as_float(__builtin_amdgcn_readlane(__float_as_int(x), 32));
  float r3 = __int_as_float(__builtin_amdgcn_readlane(__float_as_int(x), 48));
  return (r0 + r1) + (r2 + r3);
}

// wave-wide min of f32 (all values finite). Rotation-only DPP: no invalid lanes.
__device__ __forceinline__ float wave_min_f32(float x) {
  x = fminf(x, __int_as_float(__builtin_amdgcn_update_dpp(0, __float_as_int(x), 0xB1, 0xF, 0xF, true)));
  x = fminf(x, __int_as_float(__builtin_amdgcn_update_dpp(0, __float_as_int(x), 0x4E, 0xF, 0xF, true)));
  x = fminf(x, __int_as_float(__builtin_amdgcn_update_dpp(0, __float_as_int(x), 0x124, 0xF, 0xF, true)));
  x = fminf(x, __int_as_float(__builtin_amdgcn_update_dpp(0, __float_as_int(x), 0x128, 0xF, 0xF, true)));
  float r0 = __int_as_float(__builtin_amdgcn_readlane(__float_as_int(x), 0));
  float r1 = __int_as_float(__builtin_amdgcn_readlane(__float_as_int(x), 16));
  float r2 = __int_as_float(__builtin_amdgcn_readlane(__float_as_int(x), 32));
  float r3 = __int_as_float(__builtin_amdgcn_readlane(__float_as_int(x), 48));
  return fminf(fminf(r0, r1), fminf(r2, r3));
}

// squared distance — ONE formula everywhere so each (query,candidate) pair
// gets a single consistent rounding
__device__ __forceinline__ float dist2(float ax, float ay, float az,
                                       float bx, float by, float bz) {
  float dx = ax - bx, dy = ay - by, dz = az - bz;
  return fmaf(dz, dz, fmaf(dy, dy, dx * dx));
}

// Branchless sorted-insert of _d into ascending a0..a7 (v_med3_f32 per slot).
#define INS8V(_d, a0, a1, a2, a3, a4, a5, a6, a7)  \
  do {                                             \
    a7 = __builtin_amdgcn_fmed3f(_d, a6, a7);      \
    a6 = __builtin_amdgcn_fmed3f(_d, a5, a6);      \
    a5 = __builtin_amdgcn_fmed3f(_d, a4, a5);      \
    a4 = __builtin_amdgcn_fmed3f(_d, a3, a4);      \
    a3 = __builtin_amdgcn_fmed3f(_d, a2, a3);      \
    a2 = __builtin_amdgcn_fmed3f(_d, a1, a2);      \
    a1 = __builtin_amdgcn_fmed3f(_d, a0, a1);      \
    a0 = fminf(a0, _d);                            \
  } while (0)

// pop 8 wave-wide minima from the distributed lists; returns the 8th smallest
__device__ __forceinline__ float merge_T(float l0, float l1, float l2, float l3,
                                         float l4, float l5, float l6, float l7,
                                         int lane) {
  float T = 0.f;
  #pragma unroll
  for (int r = 0; r < KNB; ++r) {
    float m = wave_min_f32(l0);
    T = m;
    unsigned long long msk = __ballot(l0 == m);
    int p = (int)__builtin_ctzll(msk);
    if (lane == p) { l0 = l1; l1 = l2; l2 = l3; l3 = l4; l4 = l5; l5 = l6; l6 = l7; l7 = FLT_MAX; }
  }
  return T;
}

// slow path: exact single-query KNN over a global range (rare: graph straddle
// or window overflow). Whole wave participates.
__device__ void knn_global_single(const float* __restrict__ coord,
                                  float qx, float qy, float qz,
                                  int s, int e, int lane,
                                  int* __restrict__ knn_row) {
  float l0 = FLT_MAX, l1 = FLT_MAX, l2 = FLT_MAX, l3 = FLT_MAX,
        l4 = FLT_MAX, l5 = FLT_MAX, l6 = FLT_MAX, l7 = FLT_MAX;
  for (int base = s; base < e; base += 64) {
    int j = base + lane;
    bool ok = j < e;
    int jc = ok ? j : s;
    float d = dist2(coord[jc*3+0], coord[jc*3+1], coord[jc*3+2], qx, qy, qz);
    d = ok ? d : FLT_MAX;
    INS8V(d, l0, l1, l2, l3, l4, l5, l6, l7);
  }
  float T = merge_T(l0, l1, l2, l3, l4, l5, l6, l7, lane);
  unsigned long long lt = (1ull << lane) - 1ull;
  int cnt = 0;
  for (int base = s; base < e; base += 64) {
    int j = base + lane;
    bool ok = j < e;
    int jc = ok ? j : s;
    float d = dist2(coord[jc*3+0], coord[jc*3+1], coord[jc*3+2], qx, qy, qz);
    bool win = ok && (d <= T);
    unsigned long long msk = __ballot(win);
    if (msk) {
      int slot = cnt + __popcll(msk & lt);
      if (win && slot < KNB) knn_row[slot] = j;
      cnt += __popcll(msk);
    }
  }
}

// ---------------- segment table: seg[b] = lower_bound(batch, b), b in [0,8] ----------------
__global__ void seg_kernel(const int* __restrict__ batch, int* __restrict__ seg) {
  int b = threadIdx.x;
  if (b > 8) return;
  int lo = 0, hi = NNODES;
  while (lo < hi) { int m = (lo + hi) >> 1; if (batch[m] < b) lo = m + 1; else hi = m; }
  seg[b] = lo;
}

// ---------------- KNN (+ fused layer-0 linear) ----------------
// Block = 512 threads (8 waves) = 16 consecutive query nodes sharing one LDS
// candidate window; each wave handles TWO queries (one tile read serves both).
// __launch_bounds__(512, 8): VGPR cap 64 -> room for 2-deep LDS prefetch while
// keeping 8 waves/SIMD (LDS allows 4 blocks/CU).
__global__ __launch_bounds__(512, 8) void knnlin_kernel(
    const float* __restrict__ coord, const int* __restrict__ batch,
    const float* __restrict__ feat,
    const float* __restrict__ Wl0, const float* __restrict__ bl0,
    const float* __restrict__ Wr0, const float* __restrict__ br0,
    const int* __restrict__ seg,
    int* __restrict__ knn, float* __restrict__ xl, float* __restrict__ xr) {
  __shared__ float4 tile[KNN_CAP];
  int t = threadIdx.x;
  int lane = t & 63;
  int wid = t >> 6;
  int n0 = blockIdx.x * 16;

  int b0 = batch[n0];
  int blast = batch[n0 + 15];
  int smin = seg[b0];
  int emax = seg[blast + 1];
  int win_end = min(emax, smin + KNN_CAP);
  int cnt_fill = win_end - smin;

  // cooperative fill of candidate window
  for (int i = t; i < cnt_fill; i += 512) {
    const float* cp = coord + (size_t)(smin + i) * 3;
    tile[i] = make_float4(cp[0], cp[1], cp[2], 0.f);
  }
  __syncthreads();

  int nA = n0 + wid * 2, nB = nA + 1;
  int bA = batch[nA], bB = batch[nB];
  int sA = seg[bA], eA = seg[bA + 1];
  bool fast = (bA == bB) && (eA - smin <= KNN_CAP);

  float ax = coord[nA*3+0], ay = coord[nA*3+1], az = coord[nA*3+2];
  float bx = coord[nB*3+0], by = coord[nB*3+1], bz = coord[nB*3+2];

  if (fast) {
    int lo_i = sA - smin;
    int M = eA - sA;        // M >= 16 (block's own nodes are inside)
    int F = M >> 6, R = M & 63;

    // ---- pass 1: per-lane branchless top-8 distances, both queries,
    //      2-deep software pipeline on the tile read ----
    float a0 = FLT_MAX, a1 = FLT_MAX, a2 = FLT_MAX, a3 = FLT_MAX,
          a4 = FLT_MAX, a5 = FLT_MAX, a6 = FLT_MAX, a7 = FLT_MAX;
    float b0r = FLT_MAX, b1 = FLT_MAX, b2 = FLT_MAX, b3 = FLT_MAX,
          b4 = FLT_MAX, b5 = FLT_MAX, b6 = FLT_MAX, b7 = FLT_MAX;
    if (F > 0) {
      float4 c = tile[lo_i + lane];
      for (int it = 0; it < F; ++it) {
        int nxt = (it + 1 < F) ? (it + 1) : it;
        float4 cn = tile[lo_i + nxt * 64 + lane];   // prefetch next
        float dA = dist2(c.x, c.y, c.z, ax, ay, az);
        float dB = dist2(c.x, c.y, c.z, bx, by, bz);
        INS8V(dA, a0, a1, a2, a3, a4, a5, a6, a7);
        INS8V(dB, b0r, b1, b2, b3, b4, b5, b6, b7);
        c = cn;
      }
    }
    if (R) {
      int li = F * 64 + lane;
      bool ok = li < M;
      float4 c = tile[ok ? (lo_i + li) : lo_i];
      float dA = dist2(c.x, c.y, c.z, ax, ay, az);
      float dB = dist2(c.x, c.y, c.z, bx, by, bz);
      dA = ok ? dA : FLT_MAX;
      dB = ok ? dB : FLT_MAX;
      INS8V(dA, a0, a1, a2, a3, a4, a5, a6, a7);
      INS8V(dB, b0r, b1, b2, b3, b4, b5, b6, b7);
    }

    // ---- merge: exact 8th-smallest per query ----
    float TA = merge_T(a0, a1, a2, a3, a4, a5, a6, a7, lane);
    float TB = merge_T(b0r, b1, b2, b3, b4, b5, b6, b7, lane);

    // ---- pass 2: collect first-8-by-index with d <= T; early exit ----
    unsigned long long lt = (1ull << lane) - 1ull;
    int cntA = 0, cntB = 0;
    if (F > 0) {
      float4 c = tile[lo_i + lane];
      for (int it = 0; it < F; ++it) {
        int nxt = (it + 1 < F) ? (it + 1) : it;
        float4 cn = tile[lo_i + nxt * 64 + lane];
        float dA = dist2(c.x, c.y, c.z, ax, ay, az);
        float dB = dist2(c.x, c.y, c.z, bx, by, bz);
        int gidx = sA + it * 64 + lane;
        unsigned long long mA = __ballot(dA <= TA);
        if (mA) {
          int slot = cntA + __popcll(mA & lt);
          if ((dA <= TA) && slot < KNB) knn[nA*KNB + slot] = gidx;
          cntA += __popcll(mA);
        }
        unsigned long long mB = __ballot(dB <= TB);
        if (mB) {
          int slot = cntB + __popcll(mB & lt);
          if ((dB <= TB) && slot < KNB) knn[nB*KNB + slot] = gidx;
          cntB += __popcll(mB);
        }
        if (cntA >= KNB && cntB >= KNB) break;   // all 8 found for both
        c = cn;
      }
    }
    if (R && (cntA < KNB || cntB < KNB)) {
      int li = F * 64 + lane;
      bool ok = li < M;
      float4 c = tile[ok ? (lo_i + li) : lo_i];
      float dA = dist2(c.x, c.y, c.z, ax, ay, az);
      float dB = dist2(c.x, c.y, c.z, bx, by, bz);
      int gidx = sA + li;
      bool wA = ok && (dA <= TA);
      bool wB = ok && (dB <= TB);
      unsigned long long mA = __ballot(wA);
      if (mA) {
        int slot = cntA + __popcll(mA & lt);
        if (wA && slot < KNB) knn[nA*KNB + slot] = gidx;
        cntA += __popcll(mA);
      }
      unsigned long long mB = __ballot(wB);
      if (mB) {
        int slot = cntB + __popcll(mB & lt);
        if (wB && slot < KNB) knn[nB*KNB + slot] = gidx;
        cntB += __popcll(mB);
      }
    }
  } else {
    // rare: graph straddle / window overflow — global exact scan per query
    int sB2 = seg[bB], eB2 = seg[bB + 1];
    knn_global_single(coord, ax, ay, az, sA, eA, lane, knn + (size_t)nA * KNB);
    knn_global_single(coord, bx, by, bz, sB2, eB2, lane, knn + (size_t)nB * KNB);
  }

  // ---- fused layer-0 linear: xl/xr = feat @ Wl0/Wr0 + b for this block's 16 nodes ----
  {
    int cg = t & 63;                 // 64 col-groups of 4 (0..31 -> xl, 32..63 -> xr)
    bool isR = cg >= 32;
    const float* W  = isR ? Wr0 : Wl0;
    const float* bi = isR ? br0 : bl0;
    float* dst      = isR ? xr : xl;
    int wc = (cg & 31) * 4;
    float4 w0 = *(const float4*)(W + 0 * HIDC + wc);
    float4 w1 = *(const float4*)(W + 1 * HIDC + wc);
    float4 w2 = *(const float4*)(W + 2 * HIDC + wc);
    float4 w3 = *(const float4*)(W + 3 * HIDC + wc);
    float4 w4 = *(const float4*)(W + 4 * HIDC + wc);
    float4 w5 = *(const float4*)(W + 5 * HIDC + wc);
    float4 bb = *(const float4*)(bi + wc);
    #pragma unroll
    for (int s2 = 0; s2 < 2; ++s2) {
      int node = n0 + wid * 2 + s2;
      const float* fr = feat + (size_t)node * 6;
      float f0 = fr[0], f1 = fr[1], f2 = fr[2], f3 = fr[3], f4 = fr[4], f5 = fr[5];
      float4 acc = make_float4(0.f, 0.f, 0.f, 0.f);
      acc.x = fmaf(f0, w0.x, acc.x); acc.y = fmaf(f0, w0.y, acc.y);
      acc.z = fmaf(f0, w0.z, acc.z); acc.w = fmaf(f0, w0.w, acc.w);
      acc.x = fmaf(f1, w1.x, acc.x); acc.y = fmaf(f1, w1.y, acc.y);
      acc.z = fmaf(f1, w1.z, acc.z); acc.w = fmaf(f1, w1.w, acc.w);
      acc.x = fmaf(f2, w2.x, acc.x); acc.y = fmaf(f2, w2.y, acc.y);
      acc.z = fmaf(f2, w2.z, acc.z); acc.w = fmaf(f2, w2.w, acc.w);
      acc.x = fmaf(f3, w3.x, acc.x); acc.y = fmaf(f3, w3.y, acc.y);
      acc.z = fmaf(f3, w3.z, acc.z); acc.w = fmaf(f3, w3.w, acc.w);
      acc.x = fmaf(f4, w4.x, acc.x); acc.y = fmaf(f4, w4.y, acc.y);
      acc.z = fmaf(f4, w4.z, acc.z); acc.w = fmaf(f4, w4.w, acc.w);
      acc.x = fmaf(f5, w5.x, acc.x); acc.y = fmaf(f5, w5.y, acc.y);
      acc.z = fmaf(f5, w5.z, acc.z); acc.w = fmaf(f5, w5.w, acc.w);
      float4 o;
      o.x = acc.x + bb.x; o.y = acc.y + bb.y;
      o.z = acc.z + bb.z; o.w = acc.w + bb.w;
      *(float4*)(dst + (size_t)node * HIDC + wc) = o;
    }
  }
}

// ---------------- xl = x@Wl + bl ; xr = x@Wr + br  (16-node tiles, 4 blocks/CU) ----------
__global__ __launch_bounds__(256) void lin2_kernel(
    const float* __restrict__ x,
    const float* __restrict__ Wl, const float* __restrict__ bl,
    const float* __restrict__ Wr, const float* __restrict__ br,
    float* __restrict__ xl, float* __restrict__ xr) {
  __shared__ float xs[16 * HIDC];
  int t = threadIdx.x;
  int node0 = blockIdx.x * 16;
  for (int i = t; i < 16 * HIDC; i += 256) xs[i] = x[node0 * HIDC + i];
  __syncthreads();
  int cg = t & 63;        // 64 col-groups x 4 cols = 256 combined cols
  int ng = t >> 6;        // 4 node-groups x 4 nodes
  int c0 = cg * 4;
  bool isR = (c0 >= HIDC);
  const float* W    = isR ? Wr : Wl;
  const float* bias = isR ? br : bl;
  float* dst        = isR ? xr : xl;
  int wc = isR ? (c0 - HIDC) : c0;

  float4 acc[4];
  #pragma unroll
  for (int nn = 0; nn < 4; ++nn) acc[nn] = make_float4(0.f, 0.f, 0.f, 0.f);

  for (int k0 = 0; k0 < HIDC; k0 += 4) {
    float4 xv[4];
    #pragma unroll
    for (int nn = 0; nn < 4; ++nn)
      xv[nn] = *(const float4*)&xs[(ng * 4 + nn) * HIDC + k0];  // uniform-addr broadcast
    #pragma unroll
    for (int q = 0; q < 4; ++q) {
      float4 w = *(const float4*)(W + (size_t)(k0 + q) * HIDC + wc);
      #pragma unroll
      for (int nn = 0; nn < 4; ++nn) {
        float xq = (q == 0) ? xv[nn].x : (q == 1) ? xv[nn].y : (q == 2) ? xv[nn].z : xv[nn].w;
        acc[nn].x = fmaf(xq, w.x, acc[nn].x);
        acc[nn].y = fmaf(xq, w.y, acc[nn].y);
        acc[nn].z = fmaf(xq, w.z, acc[nn].z);
        acc[nn].w = fmaf(xq, w.w, acc[nn].w);
      }
    }
  }
  float4 b4 = *(const float4*)(bias + wc);
  #pragma unroll
  for (int nn = 0; nn < 4; ++nn) {
    int node = node0 + ng * 4 + nn;
    float4 o;
    o.x = acc[nn].x + b4.x; o.y = acc[nn].y + b4.y;
    o.z = acc[nn].z + b4.z; o.w = acc[nn].w + b4.w;
    *(float4*)(dst + (size_t)node * HIDC + wc) = o;
  }
}

// -------- GATv2 attention + aggregate + bias + relu (wave per node), optional fused final --
template<bool FINAL>
__global__ __launch_bounds__(256) void gat_attn_kernel(
    const float* __restrict__ xl, const float* __restrict__ xr,
    const int* __restrict__ knn, const float* __restrict__ att,
    const float* __restrict__ bias, float* __restrict__ xout,
    const float* __restrict__ Wf, const float* __restrict__ bf,
    float* __restrict__ out) {
  int wid = threadIdx.x >> 6;
  int lane = threadIdx.x & 63;
  int n = blockIdx.x * 4 + wid;
  int c0 = 2 * lane, c1 = 2 * lane + 1;
  float2 xr2 = *(const float2*)(xr + (size_t)n * HIDC + c0);
  float2 a2  = *(const float2*)(att + c0);
  int myj = (lane < KNB) ? knn[n * KNB + lane] : 0;
  float g0[8], g1[8], lg[8];
  #pragma unroll
  for (int k = 0; k < 8; ++k) {
    int j = __builtin_amdgcn_readlane(myj, k);
    float2 g = *(const float2*)(xl + (size_t)j * HIDC + c0);
    g0[k] = g.x; g1[k] = g.y;
    float e0 = g.x + xr2.x; e0 = (e0 > 0.f) ? e0 : 0.2f * e0;
    float e1 = g.y + xr2.y; e1 = (e1 > 0.f) ? e1 : 0.2f * e1;
    lg[k] = wave_sum(e0 * a2.x + e1 * a2.y);
  }
  float mx = lg[0];
  #pragma unroll
  for (int k = 1; k < 8; ++k) mx = fmaxf(mx, lg[k]);
  float ssum = 0.f, w[8];
  #pragma unroll
  for (int k = 0; k < 8; ++k) { w[k] = __expf(lg[k] - mx); ssum += w[k]; }
  float inv = 1.f / ssum;
  float o0 = 0.f, o1 = 0.f;
  #pragma unroll
  for (int k = 0; k < 8; ++k) { o0 += w[k] * g0[k]; o1 += w[k] * g1[k]; }
  o0 = fmaxf(fmaf(o0, inv, bias[c0]), 0.f);
  o1 = fmaxf(fmaf(o1, inv, bias[c1]), 0.f);
  if (!FINAL) {
    float2 o; o.x = o0; o.y = o1;
    *(float2*)(xout + (size_t)n * HIDC + c0) = o;
  } else {
    #pragma unroll
    for (int cls = 0; cls < 3; ++cls) {
      float p = wave_sum(o0 * Wf[c0 * 3 + cls] + o1 * Wf[c1 * 3 + cls]);
      if (lane == 0) out[n * 3 + cls] = p + bf[cls];
    }
  }
}

extern "C" void kernel_launch(void* const* d_in, const int* in_sizes, int n_in,
                              void* d_out, int out_size, void* d_ws, size_t ws_size,
                              hipStream_t stream) {
  const float* coord = (const float*)d_in[0];
  const float* feat  = (const float*)d_in[1];
  const int*   batch = (const int*)d_in[2];
  const float* Wl0 = (const float*)d_in[3];
  const float* bl0 = (const float*)d_in[4];
  const float* Wr0 = (const float*)d_in[5];
  const float* br0 = (const float*)d_in[6];
  const float* att0  = (const float*)d_in[7];
  const float* bias0 = (const float*)d_in[8];
  const float* Wl1 = (const float*)d_in[9];
  const float* bl1 = (const float*)d_in[10];
  const float* Wr1 = (const float*)d_in[11];
  const float* br1 = (const float*)d_in[12];
  const float* att1  = (const float*)d_in[13];
  const float* bias1 = (const float*)d_in[14];
  const float* Wl2 = (const float*)d_in[15];
  const float* bl2 = (const float*)d_in[16];
  const float* Wr2 = (const float*)d_in[17];
  const float* br2 = (const float*)d_in[18];
  const float* att2  = (const float*)d_in[19];
  const float* bias2 = (const float*)d_in[20];
  const float* Wf = (const float*)d_in[21];
  const float* bf = (const float*)d_in[22];
  float* out = (float*)d_out;

  char* ws = (char*)d_ws;
  int*   knn = (int*)ws;                                   // 512 KB
  float* xl  = (float*)(ws + (512 << 10));                 // 8 MB
  float* xr  = xl + (size_t)NNODES * HIDC;                 // 8 MB
  float* xb0 = xr + (size_t)NNODES * HIDC;                 // 8 MB
  float* xb1 = xb0 + (size_t)NNODES * HIDC;                // 8 MB
  int*   seg = (int*)xb1;  // 9 ints; xb1 not live until gat1 writes it

  seg_kernel<<<1, 16, 0, stream>>>(batch, seg);
  knnlin_kernel<<<NNODES / 16, 512, 0, stream>>>(coord, batch, feat,
                                                 Wl0, bl0, Wr0, br0, seg, knn, xl, xr);
  gat_attn_kernel<false><<<NNODES / 4, 256, 0, stream>>>(xl, xr, knn, att0, bias0, xb0,
                                                         nullptr, nullptr, nullptr);

  lin2_kernel<<<NNODES / 16, 256, 0, stream>>>(xb0, Wl1, bl1, Wr1, br1, xl, xr);
  gat_attn_kernel<false><<<NNODES / 4, 256, 0, stream>>>(xl, xr, knn, att1, bias1, xb1,
                                                         nullptr, nullptr, nullptr);

  lin2_kernel<<<NNODES / 16, 256, 0, stream>>>(xb1, Wl2, bl2, Wr2, br2, xl, xr);
  gat_attn_kernel<true><<<NNODES / 4, 256, 0, stream>>>(xl, xr, knn, att2, bias2, nullptr,
                                                        Wf, bf, out);
}